// Round 8
// baseline (342.831 us; speedup 1.0000x reference)
//
#include <hip/hip_runtime.h>

// ViewMorphing forward — MI355X (gfx950)
// out[0 .. 3*N*HW-1] = warped+masked image sum, out[3*N*HW] = oob loss scalar.
//
// v8: v7 (LDS-windowed gather, 133us) was barrier/latency bound at 12
//     waves/CU with 9.4M bank-conflict cycles. Three coordinated fixes:
//  1. channel-phasing: stage ONE channel of BOTH images per phase
//     (2 x 8rows x 520 floats = 33KB) -> 4 blocks/CU (16 waves). Coords &
//     weights computed once into registers, reused across 3 phases.
//  2. T14 async-stage: issue phase ch+1's global loads right after the
//     post-write barrier so they land under phase ch's sampling.
//  3. LDS row stride 520 (pad 8): row-step shifts banks by 8, killing the
//     same-col/diff-row collisions (512 = 0 mod 32 made every one collide).
//  - keeps: consecutive-pixel mapping, XCD slab swizzle, saddr bases,
//    NT streams, rare out-of-window global fallback (identical math).

constexpr int D    = 512;
constexpr int HW   = D * D;            // 262144 = 2^18
constexpr int NB   = 32;
constexpr int NPIX = NB * HW;          // 8,388,608
// loss scale: 0.01 / (N*2*HW) / (D*D)
constexpr float LOSS_SCALE = (float)(0.01 / (2.0 * (double)NPIX * (double)HW));

typedef float f4 __attribute__((ext_vector_type(4)));

constexpr int WROWS   = 8;
constexpr int RSTRIDE = 520;               // 512 + 8 pad floats (bank shift 8/row)
constexpr int PLANE   = WROWS * RSTRIDE;   // floats per image (one channel)
constexpr int LDSZ    = 2 * PLANE;         // 33,280 B

__device__ __forceinline__ float lerp2(float v00, float v01, float v10, float v11,
                                       float ax, float ay)
{
    float top = fmaf(ay, v01 - v00, v00);
    float bot = fmaf(ay, v11 - v10, v10);
    return fmaf(ax, bot - top, top);
}

__global__ void __launch_bounds__(256)
vm_fwd(const float* __restrict__ im1, const float* __restrict__ im2,
       const float* __restrict__ C,   const float* __restrict__ M1,
       const float* __restrict__ M2,  float* __restrict__ out)
{
    __shared__ float lds[LDSZ];
    __shared__ float wave_sums[4];

    // XCD slab swizzle (bijective: 8192 = 8*1024): XCD x owns 4 whole images.
    const int b    = blockIdx.x;
    const int slab = ((b & 7) << 10) | (b >> 3);

    const int n   = slab >> 8;
    const int k   = slab & 255;                 // row-pair index within image
    const int r   = k << 1;                     // first owned pixel row
    const int tid = threadIdx.x;
    const int hw0 = (k << 10) | tid;
    const int wlo = min(max(r - 3, 0), D - WROWS);   // staged-window first row

    const float* Cn = C   + (size_t)n * 2 * HW;
    const float* Mp = M1  + (size_t)n * HW;
    const float* Mq = M2  + (size_t)n * HW;
    const float* p1 = im1 + (size_t)n * 3 * HW;
    const float* p2 = im2 + (size_t)n * 3 * HW;
    float* op       = out + (size_t)n * 3 * HW;

    // ---- coord precompute (once; reused across 3 channel phases) ----
    float oob = 0.0f;
    float axA[4], ayA[4], w1v[4], axB[4], ayB[4], w2v[4];
    int   baseA[4], offA[4], baseB[4], offB[4];
    bool  inA[4], inB[4];

    #pragma unroll
    for (int j = 0; j < 4; ++j) {
        const int hw = hw0 + j * 256;
        const float qx = (float)(hw >> 9);
        const float qy = (float)(hw & 511);
        float c0 = __builtin_nontemporal_load(Cn + hw);
        float c1 = __builtin_nontemporal_load(Cn + HW + hw);
        float m1 = __builtin_nontemporal_load(Mp + hw);
        float m2 = __builtin_nontemporal_load(Mq + hw);

        const float hi = 510.999f;              // D - 1.001
        // --- A: im1 at q + c ---
        {
            float q0o = qx + c0, q1o = qy + c1;
            float q0 = fminf(fmaxf(q0o, 0.001f), hi);
            float q1 = fminf(fmaxf(q1o, 0.001f), hi);
            float d0 = q0o - q0, d1 = q1o - q1;
            oob = fmaf(d0, d0, oob); oob = fmaf(d1, d1, oob);
            float fx = floorf(q0), fy = floorf(q1);
            axA[j] = q0 - fx; ayA[j] = q1 - fy;
            // reference ceil==floor case: coincident taps, weights sum to 2
            float sc = ((axA[j] == 0.0f) ? 2.0f : 1.0f) * ((ayA[j] == 0.0f) ? 2.0f : 1.0f);
            w1v[j] = m1 * sc;
            int ix = (int)fx, iy = (int)fy;
            offA[j]  = iy + (ix << 9);          // global flat (row-major)
            int u    = ix - wlo;
            inA[j]   = (unsigned)u <= (unsigned)(WROWS - 2);
            baseA[j] = u * RSTRIDE + iy;        // img1 plane (offset 0)
        }
        // --- B: im2 at q - c ---
        {
            float q0o = qx - c0, q1o = qy - c1;
            float q0 = fminf(fmaxf(q0o, 0.001f), hi);
            float q1 = fminf(fmaxf(q1o, 0.001f), hi);
            float d0 = q0o - q0, d1 = q1o - q1;
            oob = fmaf(d0, d0, oob); oob = fmaf(d1, d1, oob);
            float fx = floorf(q0), fy = floorf(q1);
            axB[j] = q0 - fx; ayB[j] = q1 - fy;
            float sc = ((axB[j] == 0.0f) ? 2.0f : 1.0f) * ((ayB[j] == 0.0f) ? 2.0f : 1.0f);
            w2v[j] = m2 * sc;
            int ix = (int)fx, iy = (int)fy;
            offB[j]  = iy + (ix << 9);
            int u    = ix - wlo;
            inB[j]   = (unsigned)u <= (unsigned)(WROWS - 2);
            baseB[j] = PLANE + u * RSTRIDE + iy; // img2 plane
        }
    }

    // ---- staging helpers (q=0..7 compile-time: img = q>>2) ----
    // per thread: row-slot u = (q&3)*2 + (tid>>7), col = (tid&127)*4
    const int su  = (tid >> 7);                 // 0 or 1
    const int sc4 = (tid & 127) << 2;           // col

    f4 pf[8];
    #define PFLOAD(CH)                                                          \
        _Pragma("unroll")                                                       \
        for (int q = 0; q < 8; ++q) {                                           \
            const float* ip = (q < 4) ? p1 : p2;                                \
            int u = ((q & 3) << 1) + su;                                        \
            pf[q] = *(const f4*)(ip + (size_t)(CH) * HW + ((wlo + u) << 9) + sc4); \
        }
    #define PFWRITE()                                                           \
        _Pragma("unroll")                                                       \
        for (int q = 0; q < 8; ++q) {                                           \
            int u = ((q & 3) << 1) + su;                                        \
            int img = (q < 4) ? 0 : 1;                                          \
            *(f4*)(lds + img * PLANE + u * RSTRIDE + sc4) = pf[q];              \
        }

    PFLOAD(0);

    #pragma unroll
    for (int ch = 0; ch < 3; ++ch) {
        PFWRITE();
        __syncthreads();                        // staged data visible; pf regs free
        if (ch < 2) PFLOAD(ch + 1);             // T14: lands under sampling below

        const float* g1 = p1 + (size_t)ch * HW; // fallback bases (SGPR)
        const float* g2 = p2 + (size_t)ch * HW;
        float* oc = op + (size_t)ch * HW;

        #pragma unroll
        for (int j = 0; j < 4; ++j) {
            float ra, rb;
            if (inA[j]) {
                int ba = baseA[j];
                ra = lerp2(lds[ba], lds[ba + 1], lds[ba + RSTRIDE], lds[ba + RSTRIDE + 1],
                           axA[j], ayA[j]);
            } else {
                const float* pa = g1 + offA[j];
                ra = lerp2(pa[0], pa[1], pa[512], pa[513], axA[j], ayA[j]);
            }
            if (inB[j]) {
                int bb = baseB[j];
                rb = lerp2(lds[bb], lds[bb + 1], lds[bb + RSTRIDE], lds[bb + RSTRIDE + 1],
                           axB[j], ayB[j]);
            } else {
                const float* pb = g2 + offB[j];
                rb = lerp2(pb[0], pb[1], pb[512], pb[513], axB[j], ayB[j]);
            }
            __builtin_nontemporal_store(fmaf(ra, w1v[j], rb * w2v[j]),
                                        oc + hw0 + j * 256);
        }
        __syncthreads();                        // all reads done before next overwrite
    }

    // block-level reduction of oob, then one atomic per block
    #pragma unroll
    for (int off = 32; off > 0; off >>= 1)
        oob += __shfl_down(oob, off, 64);

    int lane = tid & 63;
    int wave = tid >> 6;
    if (lane == 0) wave_sums[wave] = oob;
    __syncthreads();
    if (tid == 0) {
        float s = wave_sums[0] + wave_sums[1] + wave_sums[2] + wave_sums[3];
        atomicAdd(out + (size_t)3 * NPIX, s * LOSS_SCALE);
    }
}

extern "C" void kernel_launch(void* const* d_in, const int* in_sizes, int n_in,
                              void* d_out, int out_size, void* d_ws, size_t ws_size,
                              hipStream_t stream) {
    const float* im1 = (const float*)d_in[0];
    const float* im2 = (const float*)d_in[1];
    const float* C   = (const float*)d_in[2];
    const float* M1  = (const float*)d_in[3];
    const float* M2  = (const float*)d_in[4];
    float* out = (float*)d_out;

    // zero the loss scalar (harness poisons d_out with 0xAA before every launch)
    hipMemsetAsync(out + (size_t)3 * NPIX, 0, sizeof(float), stream);

    // NPIX / (256 threads * 4 px) = 8192 blocks, exact cover
    vm_fwd<<<8192, 256, 0, stream>>>(im1, im2, C, M1, M2, out);
}